// Round 4
// baseline (2737.366 us; speedup 1.0000x reference)
//
#include <hip/hip_runtime.h>
#include <math.h>

// Problem constants (from reference setup_inputs)
#define B     256     // queries
#define KD    128     // key dim
#define VD    128     // value dim
#define TOPK  8
#define NBK   512     // key-chunk blocks (grid.x)  [R4: 128 -> 512 for occupancy]
#define QG    4       // query groups of 64 queries (grid.y)
#define KB    16      // keys per strip (MFMA M)

typedef __attribute__((ext_vector_type(8))) short bf16x8;  // 8 bf16 = 4 VGPRs
typedef __attribute__((ext_vector_type(4))) float f32x4;   // MFMA acc

// (score, index) ordering with lax.top_k tie-break (lower index wins on ties)
__device__ __forceinline__ bool gt_si(float a, int ai, float b, int bi) {
    return (a > b) || (a == b && ai < bi);
}

__device__ __forceinline__ float bf16lo_f(unsigned int p) { return __uint_as_float(p << 16); }
__device__ __forceinline__ float bf16hi_f(unsigned int p) { return __uint_as_float(p & 0xffff0000u); }

// split pair (x0,x1) -> 3 packed bf16 pairs (b1|b1', b2|b2', b3|b3')
// x ~= b1 + b2 + b3 to ~2^-24 relative.
#define SPLIT_PAIR(x0, x1, o1, o2, o3)                                         \
    {                                                                          \
        unsigned int p1_, p2_, p3_;                                            \
        float xx0_ = (x0), xx1_ = (x1);                                        \
        asm("v_cvt_pk_bf16_f32 %0, %1, %2" : "=v"(p1_) : "v"(xx0_), "v"(xx1_));\
        float r0_ = xx0_ - bf16lo_f(p1_);                                      \
        float r1_ = xx1_ - bf16hi_f(p1_);                                      \
        asm("v_cvt_pk_bf16_f32 %0, %1, %2" : "=v"(p2_) : "v"(r0_), "v"(r1_));  \
        float t0_ = r0_ - bf16lo_f(p2_);                                       \
        float t1_ = r1_ - bf16hi_f(p2_);                                       \
        asm("v_cvt_pk_bf16_f32 %0, %1, %2" : "=v"(p3_) : "v"(t0_), "v"(t1_));  \
        o1 = p1_; o2 = p2_; o3 = p3_;                                          \
    }

// ---------------------------------------------------------------------------
// Kernel 1: normalize queries + build B-operand fragments (bf16x3 split) in
// the per-lane layout k_cand consumes for the B operand of
// mfma_f32_16x16x32_bf16:  lane l supplies query col=l&15, dims
// ks*32 + (l>>4)*8 + i  (same (lane,elem)->dim map as the A staging, so the
// contraction pairs matching dims regardless of the HW's internal k order).
// qb layout: [term][qt][ks][lane][8 bf16]  (uint4 per lane slot)
// grid = 16 (qt), block = 64.
// ---------------------------------------------------------------------------
__global__ __launch_bounds__(64) void k_prep_q(const float* __restrict__ q,
                                               unsigned int* __restrict__ qb) {
    const int qt   = blockIdx.x;     // query tile 0..15
    const int l    = threadIdx.x;    // 0..63
    const int qcol = l & 15;         // query within tile
    const int ck   = l >> 4;         // 32-dim chunk (== ks this thread produces)
    const int qrow = qt * 16 + qcol;

    const float4* src = (const float4*)(q + (size_t)qrow * KD + ck * 32);
    float4 v[8];
    float ss = 0.f;
#pragma unroll
    for (int i = 0; i < 8; ++i) {
        v[i] = src[i];
        ss += v[i].x * v[i].x + v[i].y * v[i].y + v[i].z * v[i].z + v[i].w * v[i].w;
    }
    // 4 lanes (l, l^16, l^32, l^48) hold the same query's chunks
    ss += __shfl_xor(ss, 16);
    ss += __shfl_xor(ss, 32);
    const float inv = 1.0f / fmaxf(sqrtf(ss), 1e-12f);

    float x[32];
#pragma unroll
    for (int i = 0; i < 8; ++i) {
        x[4 * i + 0] = v[i].x * inv;
        x[4 * i + 1] = v[i].y * inv;
        x[4 * i + 2] = v[i].z * inv;
        x[4 * i + 3] = v[i].w * inv;
    }

    // scatter: dest lane lam = h*16 + qcol gets dims ck*32 + h*8 .. +7
#pragma unroll
    for (int h = 0; h < 4; ++h) {
        unsigned int u1[4], u2[4], u3[4];
#pragma unroll
        for (int p = 0; p < 4; ++p) {
            SPLIT_PAIR(x[h * 8 + 2 * p], x[h * 8 + 2 * p + 1], u1[p], u2[p], u3[p]);
        }
        const int lam = h * 16 + qcol;
        *(uint4*)&qb[((((size_t)0 * 16 + qt) * 4 + ck) * 64 + lam) * 4] = make_uint4(u1[0], u1[1], u1[2], u1[3]);
        *(uint4*)&qb[((((size_t)1 * 16 + qt) * 4 + ck) * 64 + lam) * 4] = make_uint4(u2[0], u2[1], u2[2], u2[3]);
        *(uint4*)&qb[((((size_t)2 * 16 + qt) * 4 + ck) * 64 + lam) * 4] = make_uint4(u3[0], u3[1], u3[2], u3[3]);
    }
}

// ---------------------------------------------------------------------------
// Kernel 2: MFMA candidate top-8.
// grid = (NBK key-chunks, QG query-groups), block = 256 (4 waves).
// Wave w owns query tile qt = qg*4 + w: its bf16x3 B-frags sit in 48 VGPRs
// for the whole kernel.  Per 16-key strip: block stages normalized+split keys
// into LDS in A-frag layout (row = key = l&15, k = (l>>4)*8+i), then each
// wave does 24 MFMAs (6 split products x 4 K-steps, 4 independent acc chains)
// and feeds 4 scores/lane into a per-lane top-8.
// __launch_bounds__(256, 8): pin VGPR cap at 64 (current natural allocation)
// so 8 blocks/CU = 32 waves/CU co-reside.
// ---------------------------------------------------------------------------
__global__ __launch_bounds__(256, 8) void k_cand(const float* __restrict__ keys,
                                                 const unsigned int* __restrict__ qb,
                                                 float* __restrict__ cand_s,
                                                 int* __restrict__ cand_i,
                                                 int N, int chunk) {
    // A-frag staging: [term][16 keys][136 bf16]  (row padded 128->136 = 272 B)
    __shared__ __align__(16) unsigned short lk[3 * 16 * 136];  // 13056 B

    const int t  = threadIdx.x;
    const int l  = t & 63;            // lane in wave
    const int w  = t >> 6;            // wave 0..3
    const int bx = blockIdx.x;        // key chunk
    const int qg = blockIdx.y;        // query group
    const int qt = qg * 4 + w;        // global query tile

    const int base = bx * chunk;
    const int nend = min(N, base + chunk);

    // persistent B fragments: 3 terms x 4 K-steps = 48 VGPRs
    bf16x8 bq[3][4];
#pragma unroll
    for (int term = 0; term < 3; ++term)
#pragma unroll
        for (int ks = 0; ks < 4; ++ks) {
            const uint4 u = *(const uint4*)&qb[((((size_t)term * 16 + qt) * 4 + ks) * 64 + l) * 4];
            bq[term][ks] = *(const bf16x8*)&u;
        }

    float s[TOPK];
    int   id[TOPK];
#pragma unroll
    for (int j = 0; j < TOPK; ++j) { s[j] = -1e30f; id[j] = 0; }

    const int srow = t >> 4;          // key row this thread stages (0..15)
    const int sseg = t & 15;          // 8-float segment within the row
    const int ro   = (l & 15) * 136 + (l >> 4) * 8;   // frag-read base (ushorts)

    for (int sb = base; sb < nend; sb += KB) {
        // ---- stage: load, normalize (same formula as before), split to bf16x3 ----
        const int row = sb + srow;
        float4 a, c;
        if (row < nend) {
            const float4* kr = (const float4*)(keys + (size_t)row * KD + sseg * 8);
            a = kr[0];
            c = kr[1];
        } else {
            a = make_float4(0.f, 0.f, 0.f, 0.f);
            c = a;
        }
        float ss = a.x * a.x + a.y * a.y + a.z * a.z + a.w * a.w
                 + c.x * c.x + c.y * c.y + c.z * c.z + c.w * c.w;
#pragma unroll
        for (int m = 8; m >= 1; m >>= 1) ss += __shfl_xor(ss, m);  // 16-lane group
        const float inv = 1.0f / fmaxf(sqrtf(ss), 1e-12f);
        const float x0 = a.x * inv, x1 = a.y * inv, x2 = a.z * inv, x3 = a.w * inv;
        const float x4 = c.x * inv, x5 = c.y * inv, x6 = c.z * inv, x7 = c.w * inv;

        unsigned int u1[4], u2[4], u3[4];
        SPLIT_PAIR(x0, x1, u1[0], u2[0], u3[0]);
        SPLIT_PAIR(x2, x3, u1[1], u2[1], u3[1]);
        SPLIT_PAIR(x4, x5, u1[2], u2[2], u3[2]);
        SPLIT_PAIR(x6, x7, u1[3], u2[3], u3[3]);

        const int wo = srow * 136 + sseg * 8;  // ushort units, 16B-aligned
        *(uint4*)&lk[0 * 2176 + wo] = make_uint4(u1[0], u1[1], u1[2], u1[3]);
        *(uint4*)&lk[1 * 2176 + wo] = make_uint4(u2[0], u2[1], u2[2], u2[3]);
        *(uint4*)&lk[2 * 2176 + wo] = make_uint4(u3[0], u3[1], u3[2], u3[3]);
        __syncthreads();

        // ---- read A fragments ----
        bf16x8 ak[3][4];
#pragma unroll
        for (int term = 0; term < 3; ++term)
#pragma unroll
            for (int ks = 0; ks < 4; ++ks)
                ak[term][ks] = *(const bf16x8*)&lk[term * 2176 + ro + ks * 32];
        __syncthreads();   // reads done; next iter may overwrite lk

        // ---- 6 split products x 4 K-steps; 4 independent acc chains ----
        f32x4 acc0 = {0.f, 0.f, 0.f, 0.f};
        f32x4 acc1 = {0.f, 0.f, 0.f, 0.f};
        f32x4 acc2 = {0.f, 0.f, 0.f, 0.f};
        f32x4 acc3 = {0.f, 0.f, 0.f, 0.f};
#define PRD(ta, tb)                                                                     \
        acc0 = __builtin_amdgcn_mfma_f32_16x16x32_bf16(ak[ta][0], bq[tb][0], acc0, 0, 0, 0); \
        acc1 = __builtin_amdgcn_mfma_f32_16x16x32_bf16(ak[ta][1], bq[tb][1], acc1, 0, 0, 0); \
        acc2 = __builtin_amdgcn_mfma_f32_16x16x32_bf16(ak[ta][2], bq[tb][2], acc2, 0, 0, 0); \
        acc3 = __builtin_amdgcn_mfma_f32_16x16x32_bf16(ak[ta][3], bq[tb][3], acc3, 0, 0, 0);
        // smallest-magnitude products first
        PRD(0, 2) PRD(2, 0) PRD(1, 1) PRD(0, 1) PRD(1, 0) PRD(0, 0)
#undef PRD
        f32x4 sim4 = (acc0 + acc1) + (acc2 + acc3);

        // ---- insert 4 scores: lane covers keys sb + (l>>4)*4 + {0..3} ----
        const int kb0 = sb + (l >> 4) * 4;
#pragma unroll
        for (int r = 0; r < 4; ++r) {
            const int kidx = kb0 + r;
            float sim = sim4[r];
            sim = (kidx < nend) ? sim : -1e30f;
            if (sim > s[TOPK - 1]) {      // ascending scan + strict > keeps tie-break
                s[TOPK - 1]  = sim;
                id[TOPK - 1] = kidx;
#pragma unroll
                for (int u = TOPK - 1; u >= 1; --u) {
                    const bool sw = s[u] > s[u - 1];
                    if (sw) {
                        float ts = s[u]; s[u] = s[u - 1]; s[u - 1] = ts;
                        int   ti = id[u]; id[u] = id[u - 1]; id[u - 1] = ti;
                    }
                }
            }
        }
    }

    // ---- merge the 4 lanes (l, l^16, l^32, l^48) sharing each query ----
#pragma unroll
    for (int m = 16; m <= 32; m <<= 1) {
        float bs[TOPK]; int bi[TOPK];
#pragma unroll
        for (int j = 0; j < TOPK; ++j) {
            bs[j] = __shfl_xor(s[j], m);
            bi[j] = __shfl_xor(id[j], m);
        }
        float ms[TOPK]; int mi[TOPK];
#pragma unroll
        for (int j = 0; j < TOPK; ++j) {
            const float av = s[j];            const int ai = id[j];
            const float bv = bs[TOPK - 1 - j]; const int b2 = bi[TOPK - 1 - j];
            const bool g = gt_si(av, ai, bv, b2);
            ms[j] = g ? av : bv;
            mi[j] = g ? ai : b2;
        }
#define CAS_(x, y)                                                     \
        { if (!gt_si(ms[x], mi[x], ms[y], mi[y])) {                    \
              float tv = ms[x]; ms[x] = ms[y]; ms[y] = tv;             \
              int   ti = mi[x]; mi[x] = mi[y]; mi[y] = ti; } }
        CAS_(0, 4); CAS_(1, 5); CAS_(2, 6); CAS_(3, 7);
        CAS_(0, 2); CAS_(1, 3); CAS_(4, 6); CAS_(5, 7);
        CAS_(0, 1); CAS_(2, 3); CAS_(4, 5); CAS_(6, 7);
#undef CAS_
#pragma unroll
        for (int j = 0; j < TOPK; ++j) { s[j] = ms[j]; id[j] = mi[j]; }
    }

    if ((l >> 4) == 0) {
        const int q = qt * 16 + (l & 15);
        float* os = cand_s + ((size_t)bx * B + q) * TOPK;
        int*   oi = cand_i + ((size_t)bx * B + q) * TOPK;
#pragma unroll
        for (int j = 0; j < TOPK; ++j) { os[j] = s[j]; oi[j] = id[j]; }
    }
}

// ---------------------------------------------------------------------------
// Kernel 3: merge NBK*8 candidates per query -> final sorted top-8,
// write scores and gather value rows.  grid=B, block=64 (one wave).
// ---------------------------------------------------------------------------
__global__ __launch_bounds__(64) void k_merge(const float* __restrict__ cand_s,
                                              const int* __restrict__ cand_i,
                                              const float* __restrict__ values,
                                              float* __restrict__ out_slots,
                                              float* __restrict__ out_scores) {
    const int q    = blockIdx.x;
    const int lane = threadIdx.x;

    float s[TOPK];
    int   id[TOPK];
#pragma unroll
    for (int j = 0; j < TOPK; ++j) { s[j] = -1e30f; id[j] = -1; }

    for (int b = lane; b < NBK; b += 64) {
        const float* cs = cand_s + ((size_t)b * B + q) * TOPK;
        const int*   ci = cand_i + ((size_t)b * B + q) * TOPK;
#pragma unroll
        for (int j = 0; j < TOPK; ++j) {
            const float v  = cs[j];
            const int   vi = ci[j];
            if (gt_si(v, vi, s[TOPK - 1], id[TOPK - 1])) {
                s[TOPK - 1]  = v;
                id[TOPK - 1] = vi;
#pragma unroll
                for (int u = TOPK - 1; u >= 1; --u) {
                    if (gt_si(s[u], id[u], s[u - 1], id[u - 1])) {
                        float ts = s[u]; s[u] = s[u - 1]; s[u - 1] = ts;
                        int   ti = id[u]; id[u] = id[u - 1]; id[u - 1] = ti;
                    }
                }
            }
        }
    }

#pragma unroll
    for (int m = 1; m <= 32; m <<= 1) {
        float bs[TOPK]; int bi[TOPK];
#pragma unroll
        for (int j = 0; j < TOPK; ++j) {
            bs[j] = __shfl_xor(s[j], m);
            bi[j] = __shfl_xor(id[j], m);
        }
        float ms[TOPK]; int mi[TOPK];
#pragma unroll
        for (int j = 0; j < TOPK; ++j) {
            const float av = s[j];            const int ai = id[j];
            const float bv = bs[TOPK - 1 - j]; const int b2 = bi[TOPK - 1 - j];
            const bool g = gt_si(av, ai, bv, b2);
            ms[j] = g ? av : bv;
            mi[j] = g ? ai : b2;
        }
#define CAS_(x, y)                                                     \
        { if (!gt_si(ms[x], mi[x], ms[y], mi[y])) {                    \
              float tv = ms[x]; ms[x] = ms[y]; ms[y] = tv;             \
              int   ti = mi[x]; mi[x] = mi[y]; mi[y] = ti; } }
        CAS_(0, 4); CAS_(1, 5); CAS_(2, 6); CAS_(3, 7);
        CAS_(0, 2); CAS_(1, 3); CAS_(4, 6); CAS_(5, 7);
        CAS_(0, 1); CAS_(2, 3); CAS_(4, 5); CAS_(6, 7);
#undef CAS_
#pragma unroll
        for (int j = 0; j < TOPK; ++j) { s[j] = ms[j]; id[j] = mi[j]; }
    }

    if (lane == 0) {
#pragma unroll
        for (int j = 0; j < TOPK; ++j) out_scores[(size_t)q * TOPK + j] = s[j];
    }

#pragma unroll
    for (int j = 0; j < TOPK; ++j) {
        const int row = id[j];
        const float2* src = (const float2*)(values + (size_t)row * VD);
        float2 v = src[lane];
        ((float2*)(out_slots + ((size_t)q * TOPK + j) * VD))[lane] = v;
    }
}

// ---------------------------------------------------------------------------
extern "C" void kernel_launch(void* const* d_in, const int* in_sizes, int n_in,
                              void* d_out, int out_size, void* d_ws, size_t ws_size,
                              hipStream_t stream) {
    const float* q      = (const float*)d_in[0];
    const float* keys   = (const float*)d_in[1];
    const float* values = (const float*)d_in[2];
    const int N = in_sizes[1] / KD;          // 500000

    float* out_slots  = (float*)d_out;                       // B*TOPK*VD
    float* out_scores = out_slots + (size_t)B * TOPK * VD;   // B*TOPK

    // workspace layout
    unsigned int* qbuf = (unsigned int*)d_ws;                // 3*16*4*64*4 = 49152 uints
    float* cand_s = (float*)(qbuf + 49152);                  // NBK*B*TOPK
    int*   cand_i = (int*)(cand_s + (size_t)NBK * B * TOPK); // NBK*B*TOPK

    const int chunk = (N + NBK - 1) / NBK;

    k_prep_q<<<16, 64, 0, stream>>>(q, qbuf);
    dim3 grid(NBK, QG);
    k_cand<<<grid, 256, 0, stream>>>(keys, qbuf, cand_s, cand_i, N, chunk);
    k_merge<<<B, 64, 0, stream>>>(cand_s, cand_i, values, out_slots, out_scores);
}

// Round 5
// 736.822 us; speedup vs baseline: 3.7151x; 3.7151x over previous
//
#include <hip/hip_runtime.h>
#include <math.h>

// Problem constants (from reference setup_inputs)
#define B     256     // queries
#define KD    128     // key dim
#define VD    128     // value dim
#define TOPK  8
#define NBK   512     // key-chunk blocks (grid.x): 2048 blocks = 8/CU
#define QG    4       // query groups of 64 queries (grid.y)
#define KB    16      // keys per strip (MFMA M)

typedef __attribute__((ext_vector_type(8))) short bf16x8;  // 8 bf16 = 4 VGPRs
typedef __attribute__((ext_vector_type(4))) float f32x4;   // MFMA acc

// (score, index) ordering with lax.top_k tie-break (lower index wins on ties)
__device__ __forceinline__ bool gt_si(float a, int ai, float b, int bi) {
    return (a > b) || (a == b && ai < bi);
}

__device__ __forceinline__ float bf16lo_f(unsigned int p) { return __uint_as_float(p << 16); }
__device__ __forceinline__ float bf16hi_f(unsigned int p) { return __uint_as_float(p & 0xffff0000u); }

// split pair (x0,x1) -> 3 packed bf16 pairs (b1|b1', b2|b2', b3|b3')
// x ~= b1 + b2 + b3 to ~2^-24 relative.
#define SPLIT_PAIR(x0, x1, o1, o2, o3)                                         \
    {                                                                          \
        unsigned int p1_, p2_, p3_;                                            \
        float xx0_ = (x0), xx1_ = (x1);                                        \
        asm("v_cvt_pk_bf16_f32 %0, %1, %2" : "=v"(p1_) : "v"(xx0_), "v"(xx1_));\
        float r0_ = xx0_ - bf16lo_f(p1_);                                      \
        float r1_ = xx1_ - bf16hi_f(p1_);                                      \
        asm("v_cvt_pk_bf16_f32 %0, %1, %2" : "=v"(p2_) : "v"(r0_), "v"(r1_));  \
        float t0_ = r0_ - bf16lo_f(p2_);                                       \
        float t1_ = r1_ - bf16hi_f(p2_);                                       \
        asm("v_cvt_pk_bf16_f32 %0, %1, %2" : "=v"(p3_) : "v"(t0_), "v"(t1_));  \
        o1 = p1_; o2 = p2_; o3 = p3_;                                          \
    }

// ---------------------------------------------------------------------------
// Kernel 1: normalize queries + build B-operand fragments (bf16x3 split) in
// the per-lane layout k_cand consumes for the B operand of
// mfma_f32_16x16x32_bf16:  lane l supplies query col=l&15, dims
// ks*32 + (l>>4)*8 + i  (same (lane,elem)->dim map as the A staging, so the
// contraction pairs matching dims regardless of the HW's internal k order).
// qb layout: [term][qt][ks][lane][8 bf16]  (uint4 per lane slot)
// grid = 16 (qt), block = 64.
// ---------------------------------------------------------------------------
__global__ __launch_bounds__(64) void k_prep_q(const float* __restrict__ q,
                                               unsigned int* __restrict__ qb) {
    const int qt   = blockIdx.x;     // query tile 0..15
    const int l    = threadIdx.x;    // 0..63
    const int qcol = l & 15;         // query within tile
    const int ck   = l >> 4;         // 32-dim chunk (== ks this thread produces)
    const int qrow = qt * 16 + qcol;

    const float4* src = (const float4*)(q + (size_t)qrow * KD + ck * 32);
    float4 v[8];
    float ss = 0.f;
#pragma unroll
    for (int i = 0; i < 8; ++i) {
        v[i] = src[i];
        ss += v[i].x * v[i].x + v[i].y * v[i].y + v[i].z * v[i].z + v[i].w * v[i].w;
    }
    // 4 lanes (l, l^16, l^32, l^48) hold the same query's chunks
    ss += __shfl_xor(ss, 16);
    ss += __shfl_xor(ss, 32);
    const float inv = 1.0f / fmaxf(sqrtf(ss), 1e-12f);

    float x[32];
#pragma unroll
    for (int i = 0; i < 8; ++i) {
        x[4 * i + 0] = v[i].x * inv;
        x[4 * i + 1] = v[i].y * inv;
        x[4 * i + 2] = v[i].z * inv;
        x[4 * i + 3] = v[i].w * inv;
    }

    // scatter: dest lane lam = h*16 + qcol gets dims ck*32 + h*8 .. +7
#pragma unroll
    for (int h = 0; h < 4; ++h) {
        unsigned int u1[4], u2[4], u3[4];
#pragma unroll
        for (int p = 0; p < 4; ++p) {
            SPLIT_PAIR(x[h * 8 + 2 * p], x[h * 8 + 2 * p + 1], u1[p], u2[p], u3[p]);
        }
        const int lam = h * 16 + qcol;
        *(uint4*)&qb[((((size_t)0 * 16 + qt) * 4 + ck) * 64 + lam) * 4] = make_uint4(u1[0], u1[1], u1[2], u1[3]);
        *(uint4*)&qb[((((size_t)1 * 16 + qt) * 4 + ck) * 64 + lam) * 4] = make_uint4(u2[0], u2[1], u2[2], u2[3]);
        *(uint4*)&qb[((((size_t)2 * 16 + qt) * 4 + ck) * 64 + lam) * 4] = make_uint4(u3[0], u3[1], u3[2], u3[3]);
    }
}

// ---------------------------------------------------------------------------
// Kernel 2: MFMA candidate top-8.
// grid = (NBK key-chunks, QG query-groups), block = 256 (4 waves).
// Wave w owns query tile qt = qg*4 + w: its bf16x3 B-frags sit in 48 VGPRs
// for the whole kernel.  Per 16-key strip: block stages normalized+split keys
// into LDS in A-frag layout (row = key = l&15, k = (l>>4)*8+i), then each
// wave does 24 MFMAs (6 split products x 4 K-steps, 4 independent acc chains)
// and feeds 4 scores/lane into a per-lane top-8.
// __launch_bounds__(256, 2): natural VGPR=64, no spill (R4's (256,8) forced
// VGPR=32 -> 8.4 GB scratch traffic).  Occupancy comes from the grid:
// 2048 blocks / 256 CU = 8 blocks/CU, schedulable at VGPR=64.
// ---------------------------------------------------------------------------
__global__ __launch_bounds__(256, 2) void k_cand(const float* __restrict__ keys,
                                                 const unsigned int* __restrict__ qb,
                                                 float* __restrict__ cand_s,
                                                 int* __restrict__ cand_i,
                                                 int N, int chunk) {
    // A-frag staging: [term][16 keys][136 bf16]  (row padded 128->136 = 272 B)
    __shared__ __align__(16) unsigned short lk[3 * 16 * 136];  // 13056 B

    const int t  = threadIdx.x;
    const int l  = t & 63;            // lane in wave
    const int w  = t >> 6;            // wave 0..3
    const int bx = blockIdx.x;        // key chunk
    const int qg = blockIdx.y;        // query group
    const int qt = qg * 4 + w;        // global query tile

    const int base = bx * chunk;
    const int nend = min(N, base + chunk);

    // persistent B fragments: 3 terms x 4 K-steps = 48 VGPRs
    bf16x8 bq[3][4];
#pragma unroll
    for (int term = 0; term < 3; ++term)
#pragma unroll
        for (int ks = 0; ks < 4; ++ks) {
            const uint4 u = *(const uint4*)&qb[((((size_t)term * 16 + qt) * 4 + ks) * 64 + l) * 4];
            bq[term][ks] = *(const bf16x8*)&u;
        }

    float s[TOPK];
    int   id[TOPK];
#pragma unroll
    for (int j = 0; j < TOPK; ++j) { s[j] = -1e30f; id[j] = 0; }

    const int srow = t >> 4;          // key row this thread stages (0..15)
    const int sseg = t & 15;          // 8-float segment within the row
    const int ro   = (l & 15) * 136 + (l >> 4) * 8;   // frag-read base (ushorts)

    for (int sb = base; sb < nend; sb += KB) {
        // ---- stage: load, normalize (same formula as before), split to bf16x3 ----
        const int row = sb + srow;
        float4 a, c;
        if (row < nend) {
            const float4* kr = (const float4*)(keys + (size_t)row * KD + sseg * 8);
            a = kr[0];
            c = kr[1];
        } else {
            a = make_float4(0.f, 0.f, 0.f, 0.f);
            c = a;
        }
        float ss = a.x * a.x + a.y * a.y + a.z * a.z + a.w * a.w
                 + c.x * c.x + c.y * c.y + c.z * c.z + c.w * c.w;
#pragma unroll
        for (int m = 8; m >= 1; m >>= 1) ss += __shfl_xor(ss, m);  // 16-lane group
        const float inv = 1.0f / fmaxf(sqrtf(ss), 1e-12f);
        const float x0 = a.x * inv, x1 = a.y * inv, x2 = a.z * inv, x3 = a.w * inv;
        const float x4 = c.x * inv, x5 = c.y * inv, x6 = c.z * inv, x7 = c.w * inv;

        unsigned int u1[4], u2[4], u3[4];
        SPLIT_PAIR(x0, x1, u1[0], u2[0], u3[0]);
        SPLIT_PAIR(x2, x3, u1[1], u2[1], u3[1]);
        SPLIT_PAIR(x4, x5, u1[2], u2[2], u3[2]);
        SPLIT_PAIR(x6, x7, u1[3], u2[3], u3[3]);

        const int wo = srow * 136 + sseg * 8;  // ushort units, 16B-aligned
        *(uint4*)&lk[0 * 2176 + wo] = make_uint4(u1[0], u1[1], u1[2], u1[3]);
        *(uint4*)&lk[1 * 2176 + wo] = make_uint4(u2[0], u2[1], u2[2], u2[3]);
        *(uint4*)&lk[2 * 2176 + wo] = make_uint4(u3[0], u3[1], u3[2], u3[3]);
        __syncthreads();

        // ---- read A fragments ----
        bf16x8 ak[3][4];
#pragma unroll
        for (int term = 0; term < 3; ++term)
#pragma unroll
            for (int ks = 0; ks < 4; ++ks)
                ak[term][ks] = *(const bf16x8*)&lk[term * 2176 + ro + ks * 32];
        __syncthreads();   // reads done; next iter may overwrite lk

        // ---- 6 split products x 4 K-steps; 4 independent acc chains ----
        f32x4 acc0 = {0.f, 0.f, 0.f, 0.f};
        f32x4 acc1 = {0.f, 0.f, 0.f, 0.f};
        f32x4 acc2 = {0.f, 0.f, 0.f, 0.f};
        f32x4 acc3 = {0.f, 0.f, 0.f, 0.f};
#define PRD(ta, tb)                                                                     \
        acc0 = __builtin_amdgcn_mfma_f32_16x16x32_bf16(ak[ta][0], bq[tb][0], acc0, 0, 0, 0); \
        acc1 = __builtin_amdgcn_mfma_f32_16x16x32_bf16(ak[ta][1], bq[tb][1], acc1, 0, 0, 0); \
        acc2 = __builtin_amdgcn_mfma_f32_16x16x32_bf16(ak[ta][2], bq[tb][2], acc2, 0, 0, 0); \
        acc3 = __builtin_amdgcn_mfma_f32_16x16x32_bf16(ak[ta][3], bq[tb][3], acc3, 0, 0, 0);
        // smallest-magnitude products first
        PRD(0, 2) PRD(2, 0) PRD(1, 1) PRD(0, 1) PRD(1, 0) PRD(0, 0)
#undef PRD
        f32x4 sim4 = (acc0 + acc1) + (acc2 + acc3);

        // ---- insert 4 scores: lane covers keys sb + (l>>4)*4 + {0..3} ----
        const int kb0 = sb + (l >> 4) * 4;
#pragma unroll
        for (int r = 0; r < 4; ++r) {
            const int kidx = kb0 + r;
            float sim = sim4[r];
            sim = (kidx < nend) ? sim : -1e30f;
            if (sim > s[TOPK - 1]) {      // ascending scan + strict > keeps tie-break
                s[TOPK - 1]  = sim;
                id[TOPK - 1] = kidx;
#pragma unroll
                for (int u = TOPK - 1; u >= 1; --u) {
                    const bool sw = s[u] > s[u - 1];
                    if (sw) {
                        float ts = s[u]; s[u] = s[u - 1]; s[u - 1] = ts;
                        int   ti = id[u]; id[u] = id[u - 1]; id[u - 1] = ti;
                    }
                }
            }
        }
    }

    // ---- merge the 4 lanes (l, l^16, l^32, l^48) sharing each query ----
#pragma unroll
    for (int m = 16; m <= 32; m <<= 1) {
        float bs[TOPK]; int bi[TOPK];
#pragma unroll
        for (int j = 0; j < TOPK; ++j) {
            bs[j] = __shfl_xor(s[j], m);
            bi[j] = __shfl_xor(id[j], m);
        }
        float ms[TOPK]; int mi[TOPK];
#pragma unroll
        for (int j = 0; j < TOPK; ++j) {
            const float av = s[j];            const int ai = id[j];
            const float bv = bs[TOPK - 1 - j]; const int b2 = bi[TOPK - 1 - j];
            const bool g = gt_si(av, ai, bv, b2);
            ms[j] = g ? av : bv;
            mi[j] = g ? ai : b2;
        }
#define CAS_(x, y)                                                     \
        { if (!gt_si(ms[x], mi[x], ms[y], mi[y])) {                    \
              float tv = ms[x]; ms[x] = ms[y]; ms[y] = tv;             \
              int   ti = mi[x]; mi[x] = mi[y]; mi[y] = ti; } }
        CAS_(0, 4); CAS_(1, 5); CAS_(2, 6); CAS_(3, 7);
        CAS_(0, 2); CAS_(1, 3); CAS_(4, 6); CAS_(5, 7);
        CAS_(0, 1); CAS_(2, 3); CAS_(4, 5); CAS_(6, 7);
#undef CAS_
#pragma unroll
        for (int j = 0; j < TOPK; ++j) { s[j] = ms[j]; id[j] = mi[j]; }
    }

    if ((l >> 4) == 0) {
        const int q = qt * 16 + (l & 15);
        float* os = cand_s + ((size_t)bx * B + q) * TOPK;
        int*   oi = cand_i + ((size_t)bx * B + q) * TOPK;
#pragma unroll
        for (int j = 0; j < TOPK; ++j) { os[j] = s[j]; oi[j] = id[j]; }
    }
}

// ---------------------------------------------------------------------------
// Kernel 3: merge NBK*8 candidates per query -> final sorted top-8,
// write scores and gather value rows.  grid=B, block=64 (one wave).
// ---------------------------------------------------------------------------
__global__ __launch_bounds__(64) void k_merge(const float* __restrict__ cand_s,
                                              const int* __restrict__ cand_i,
                                              const float* __restrict__ values,
                                              float* __restrict__ out_slots,
                                              float* __restrict__ out_scores) {
    const int q    = blockIdx.x;
    const int lane = threadIdx.x;

    float s[TOPK];
    int   id[TOPK];
#pragma unroll
    for (int j = 0; j < TOPK; ++j) { s[j] = -1e30f; id[j] = -1; }

    for (int b = lane; b < NBK; b += 64) {
        const float* cs = cand_s + ((size_t)b * B + q) * TOPK;
        const int*   ci = cand_i + ((size_t)b * B + q) * TOPK;
#pragma unroll
        for (int j = 0; j < TOPK; ++j) {
            const float v  = cs[j];
            const int   vi = ci[j];
            if (gt_si(v, vi, s[TOPK - 1], id[TOPK - 1])) {
                s[TOPK - 1]  = v;
                id[TOPK - 1] = vi;
#pragma unroll
                for (int u = TOPK - 1; u >= 1; --u) {
                    if (gt_si(s[u], id[u], s[u - 1], id[u - 1])) {
                        float ts = s[u]; s[u] = s[u - 1]; s[u - 1] = ts;
                        int   ti = id[u]; id[u] = id[u - 1]; id[u - 1] = ti;
                    }
                }
            }
        }
    }

#pragma unroll
    for (int m = 1; m <= 32; m <<= 1) {
        float bs[TOPK]; int bi[TOPK];
#pragma unroll
        for (int j = 0; j < TOPK; ++j) {
            bs[j] = __shfl_xor(s[j], m);
            bi[j] = __shfl_xor(id[j], m);
        }
        float ms[TOPK]; int mi[TOPK];
#pragma unroll
        for (int j = 0; j < TOPK; ++j) {
            const float av = s[j];            const int ai = id[j];
            const float bv = bs[TOPK - 1 - j]; const int b2 = bi[TOPK - 1 - j];
            const bool g = gt_si(av, ai, bv, b2);
            ms[j] = g ? av : bv;
            mi[j] = g ? ai : b2;
        }
#define CAS_(x, y)                                                     \
        { if (!gt_si(ms[x], mi[x], ms[y], mi[y])) {                    \
              float tv = ms[x]; ms[x] = ms[y]; ms[y] = tv;             \
              int   ti = mi[x]; mi[x] = mi[y]; mi[y] = ti; } }
        CAS_(0, 4); CAS_(1, 5); CAS_(2, 6); CAS_(3, 7);
        CAS_(0, 2); CAS_(1, 3); CAS_(4, 6); CAS_(5, 7);
        CAS_(0, 1); CAS_(2, 3); CAS_(4, 5); CAS_(6, 7);
#undef CAS_
#pragma unroll
        for (int j = 0; j < TOPK; ++j) { s[j] = ms[j]; id[j] = mi[j]; }
    }

    if (lane == 0) {
#pragma unroll
        for (int j = 0; j < TOPK; ++j) out_scores[(size_t)q * TOPK + j] = s[j];
    }

#pragma unroll
    for (int j = 0; j < TOPK; ++j) {
        const int row = id[j];
        const float2* src = (const float2*)(values + (size_t)row * VD);
        float2 v = src[lane];
        ((float2*)(out_slots + ((size_t)q * TOPK + j) * VD))[lane] = v;
    }
}

// ---------------------------------------------------------------------------
extern "C" void kernel_launch(void* const* d_in, const int* in_sizes, int n_in,
                              void* d_out, int out_size, void* d_ws, size_t ws_size,
                              hipStream_t stream) {
    const float* q      = (const float*)d_in[0];
    const float* keys   = (const float*)d_in[1];
    const float* values = (const float*)d_in[2];
    const int N = in_sizes[1] / KD;          // 500000

    float* out_slots  = (float*)d_out;                       // B*TOPK*VD
    float* out_scores = out_slots + (size_t)B * TOPK * VD;   // B*TOPK

    // workspace layout
    unsigned int* qbuf = (unsigned int*)d_ws;                // 3*16*4*64*4 = 49152 uints
    float* cand_s = (float*)(qbuf + 49152);                  // NBK*B*TOPK
    int*   cand_i = (int*)(cand_s + (size_t)NBK * B * TOPK); // NBK*B*TOPK

    const int chunk = (N + NBK - 1) / NBK;

    k_prep_q<<<16, 64, 0, stream>>>(q, qbuf);
    dim3 grid(NBK, QG);
    k_cand<<<grid, 256, 0, stream>>>(keys, qbuf, cand_s, cand_i, N, chunk);
    k_merge<<<B, 64, 0, stream>>>(cand_s, cand_i, values, out_slots, out_scores);
}